// Round 9
// baseline (1798.656 us; speedup 1.0000x reference)
//
#include <hip/hip_runtime.h>

typedef __attribute__((ext_vector_type(8))) _Float16 f16x8;
typedef __attribute__((ext_vector_type(4))) float f32x4;

#define DEVINL __device__ __forceinline__

constexpr int BATCH = 16384;
constexpr int DIN   = 1024;
constexpr int DHID  = 2048;
constexpr int NEXP  = 16;
constexpr int EXPSZ = 512;
constexpr int NPAIR = BATCH * 3;

DEVINL unsigned short f2h(float v) {
  _Float16 h = (_Float16)v;
  return __builtin_bit_cast(unsigned short, h);
}
DEVINL float h2f(unsigned short u) {
  return (float)__builtin_bit_cast(_Float16, u);
}

DEVINL void gl2lds(const unsigned short* src, char* ldst) {
  __builtin_amdgcn_global_load_lds((const __attribute__((address_space(1))) void*)src,
                                   (__attribute__((address_space(3))) void*)ldst, 16, 0, 0);
}

// ---------------------------------------------------------------------------
// fp16 split-MFMA GEMM, 128x128 tile, 4 waves (2x2 of 64x64), 16x16x32 f16.
// Operands are fp16 level arrays staged via global_load_lds (fragment-
// contiguous LDS: unit u (16B) = g*128 + row -> elems [row][kt+g*8..+7]).
// 1D grid (x = NXT*NYT tiles, z = expert) with m204 bijective XCD swizzle +
// col-tile-fastest rasterization: each XCD owns a contiguous row band, so a
// row-tile's A panel is fetched into its L2 once and reused over col-tiles.
// SPLIT=1: v = c0 + c1/2048 (c1 stored x2048). 3 MFMA terms; result =
//   acc + acc2/2048. SPLIT=0: plain fp16.
// AMODE: 0 linear A rows; 1 gather A rows via pairRow; 2 pair-linear A rows.
// EPI:   0 = +bias -> fp16 hi/lo pair; 1 = +bias,relu -> fp16;
//        2 = +bias,*pairW -> fp16; 3 = +bias -> fp32.
// ---------------------------------------------------------------------------
template<int SPLIT, int AMODE, int EPI, int BK, int NYT>
__global__ __launch_bounds__(256, SPLIT ? 2 : 3)
void mgemm_k(const unsigned short* __restrict__ A0p,
             const unsigned short* __restrict__ A1p,
             const unsigned short* __restrict__ B0p,
             const unsigned short* __restrict__ B1p,
             const float* __restrict__ biasb,
             float* __restrict__ Cf, unsigned short* __restrict__ Cb0,
             unsigned short* __restrict__ Cb1,
             const int* __restrict__ pairRow, const float* __restrict__ pairW,
             const int* __restrict__ counts, const int* __restrict__ offs,
             int M, int N, int K)
{
  constexpr int KG = BK / 8;
  constexpr int UNITS = 128 * KG;
  constexpr int ISS = UNITS / 256;
  constexpr int NKK = BK / 32;
  constexpr int NARR = SPLIT ? 4 : 2;
  constexpr bool EXPERT = (AMODE == 1 || AMODE == 2);
  __shared__ char smem[NARR * UNITS * 16];
  char* sA0 = smem;
  char* sA1 = smem + UNITS * 16;                    // iff SPLIT
  char* sB0 = smem + (SPLIT ? 2 : 1) * UNITS * 16;
  char* sB1 = smem + 3 * UNITS * 16;                // iff SPLIT

  int Mloc = M, rowBase = 0;
  const unsigned short* b0 = B0p;
  const unsigned short* b1 = B1p;
  const float* bias = biasb;
  if (EXPERT) {
    const int e = blockIdx.z;
    Mloc = counts[e];
    rowBase = offs[e];
    const size_t eo = (size_t)e * (size_t)K * N;
    b0 = B0p + eo;
    if (SPLIT) b1 = B1p + eo;
    bias = biasb + (size_t)e * N;
  }

  // m204 bijective XCD swizzle -> logical work id; col-tile fastest.
  const int nwg = (int)gridDim.x;
  const int q = nwg >> 3, r = nwg & 7;
  const int xcd = (int)blockIdx.x & 7, pos = (int)blockIdx.x >> 3;
  const int lin = ((xcd < r) ? xcd * (q + 1) : r * (q + 1) + (xcd - r) * q) + pos;
  const int tile0 = (lin / NYT) * 128;
  const int col0  = (lin % NYT) * 128;
  if (tile0 >= Mloc) return;

  const int tid = threadIdx.x;
  const int lane = tid & 63;
  const int wr = ((tid >> 6) >> 1) * 64;
  const int wc = ((tid >> 6) & 1) * 64;
  const int l15 = lane & 15;
  const int lg = lane >> 4;

  // per-thread staging row (fixed across K)
  const int srow = tid & 127;
  size_t aoff;
  if (AMODE == 0) {
    aoff = (size_t)(tile0 + srow) * K;
  } else if (AMODE == 1) {
    int p = rowBase + tile0 + srow; p = p < NPAIR - 1 ? p : NPAIR - 1;
    aoff = (size_t)pairRow[p] * K;
  } else {
    int p = rowBase + tile0 + srow; p = p < NPAIR - 1 ? p : NPAIR - 1;
    aoff = (size_t)p * K;
  }
  const size_t boff = (size_t)(col0 + srow) * K;

  f32x4 acc[4][4];
  f32x4 acc2[4][4];
  #pragma unroll
  for (int m = 0; m < 4; ++m)
    #pragma unroll
    for (int n = 0; n < 4; ++n) {
      acc[m][n] = f32x4{0.f, 0.f, 0.f, 0.f};
      if (SPLIT) acc2[m][n] = f32x4{0.f, 0.f, 0.f, 0.f};
    }

  for (int kt = 0; kt < K; kt += BK) {
    #pragma unroll
    for (int it = 0; it < ISS; ++it) {
      const int uo = (it * 256 + (tid & 192)) * 16;   // wave-uniform LDS base
      const int ko = kt + (it * 2 + (tid >> 7)) * 8;
      gl2lds(A0p + aoff + ko, sA0 + uo);
      if (SPLIT) gl2lds(A1p + aoff + ko, sA1 + uo);
      gl2lds(b0 + boff + ko, sB0 + uo);
      if (SPLIT) gl2lds(b1 + boff + ko, sB1 + uo);
    }
    __syncthreads();
    #pragma unroll
    for (int kk = 0; kk < NKK; ++kk) {
      const int g = kk * 4 + lg;
      f16x8 b0f[4], b1f[4];
      #pragma unroll
      for (int n = 0; n < 4; ++n) {
        const size_t off = (size_t)(g * 128 + wc + n * 16 + l15) * 16;
        b0f[n] = *(const f16x8*)(sB0 + off);
        if (SPLIT) b1f[n] = *(const f16x8*)(sB1 + off);
      }
      #pragma unroll
      for (int m = 0; m < 4; ++m) {
        const size_t ao = (size_t)(g * 128 + wr + m * 16 + l15) * 16;
        const f16x8 a0 = *(const f16x8*)(sA0 + ao);
        f16x8 a1;
        if (SPLIT) a1 = *(const f16x8*)(sA1 + ao);
        #pragma unroll
        for (int n = 0; n < 4; ++n) {
          if (SPLIT) {
            acc2[m][n] = __builtin_amdgcn_mfma_f32_16x16x32_f16(a1, b0f[n], acc2[m][n], 0, 0, 0);
            acc2[m][n] = __builtin_amdgcn_mfma_f32_16x16x32_f16(a0, b1f[n], acc2[m][n], 0, 0, 0);
          }
          acc[m][n] = __builtin_amdgcn_mfma_f32_16x16x32_f16(a0, b0f[n], acc[m][n], 0, 0, 0);
        }
      }
    }
    __syncthreads();
  }

  // epilogue. C/D mapping: col = lane&15, row = (lane>>4)*4 + j  [m89-verified]
  #pragma unroll
  for (int n = 0; n < 4; ++n) {
    const int cn = col0 + wc + n * 16 + l15;
    const float bv = bias[cn];
    #pragma unroll
    for (int m = 0; m < 4; ++m) {
      const int r0 = wr + m * 16 + ((lane >> 4) << 2);
      #pragma unroll
      for (int j = 0; j < 4; ++j) {
        const int rm = tile0 + r0 + j;
        if (EXPERT && rm >= Mloc) continue;
        float v = acc[m][n][j];
        if (SPLIT) v += acc2[m][n][j] * (1.f / 2048.f);
        v += bv;
        const size_t ci = (size_t)(EXPERT ? (rowBase + rm) : rm) * N + cn;
        if (EPI == 0) {
          const unsigned short h0 = f2h(v);
          Cb0[ci] = h0;
          Cb1[ci] = f2h((v - h2f(h0)) * 2048.f);
        } else if (EPI == 1) {
          Cb0[ci] = f2h(fmaxf(v, 0.f));
        } else if (EPI == 2) {
          Cb0[ci] = f2h(v * pairW[rowBase + rm]);
        } else {
          Cf[ci] = v;
        }
      }
    }
  }
}

// ---------------------------------------------------------------------------
// fp32 vector GEMM (gate + towers). C = relu(A@B[t] + bias[t]), fp32.
// ---------------------------------------------------------------------------
template<bool RELU>
__global__ __launch_bounds__(256, 2)
void gemm32_k(const float* __restrict__ Av, const float* __restrict__ Bb,
              const float* __restrict__ biasb, float* __restrict__ Cv,
              const int* __restrict__ taskPtr, int M, int N, int K)
{
  __shared__ float As[16][128];
  __shared__ float Bs[16][128];
  const int t = *taskPtr;
  const float* Bw = Bb + (size_t)t * K * N;
  const float* bias = biasb + (size_t)t * N;
  const int tile0 = blockIdx.x * 128;
  const int col0 = blockIdx.y * 128;
  const int tid = threadIdx.x;
  const int am = tid >> 1, ak = (tid & 1) * 8;
  const int bk = tid >> 4, bn = (tid & 15) * 8;
  const int rg = (tid >> 4) * 8, cg = (tid & 15) * 8;
  const float* aptr = Av + (size_t)(tile0 + am) * K;

  float acc[8][8];
  #pragma unroll
  for (int i = 0; i < 8; ++i)
    #pragma unroll
    for (int j = 0; j < 8; ++j) acc[i][j] = 0.f;

  for (int kt = 0; kt < K; kt += 16) {
    {
      const float* src = aptr + kt + ak;
      float4 x0 = *reinterpret_cast<const float4*>(src);
      float4 x1 = *reinterpret_cast<const float4*>(src + 4);
      As[ak+0][am]=x0.x; As[ak+1][am]=x0.y; As[ak+2][am]=x0.z; As[ak+3][am]=x0.w;
      As[ak+4][am]=x1.x; As[ak+5][am]=x1.y; As[ak+6][am]=x1.z; As[ak+7][am]=x1.w;
    }
    {
      const float* bsrc = Bw + (size_t)(kt + bk) * N + (col0 + bn);
      float4 b0 = *reinterpret_cast<const float4*>(bsrc);
      float4 b1 = *reinterpret_cast<const float4*>(bsrc + 4);
      Bs[bk][bn+0]=b0.x; Bs[bk][bn+1]=b0.y; Bs[bk][bn+2]=b0.z; Bs[bk][bn+3]=b0.w;
      Bs[bk][bn+4]=b1.x; Bs[bk][bn+5]=b1.y; Bs[bk][bn+6]=b1.z; Bs[bk][bn+7]=b1.w;
    }
    __syncthreads();
    #pragma unroll
    for (int k = 0; k < 16; ++k) {
      float4 a0 = *reinterpret_cast<const float4*>(&As[k][rg]);
      float4 a1 = *reinterpret_cast<const float4*>(&As[k][rg + 4]);
      float4 c0 = *reinterpret_cast<const float4*>(&Bs[k][cg]);
      float4 c1 = *reinterpret_cast<const float4*>(&Bs[k][cg + 4]);
      const float a[8] = {a0.x,a0.y,a0.z,a0.w,a1.x,a1.y,a1.z,a1.w};
      const float b[8] = {c0.x,c0.y,c0.z,c0.w,c1.x,c1.y,c1.z,c1.w};
      #pragma unroll
      for (int i = 0; i < 8; ++i)
        #pragma unroll
        for (int j = 0; j < 8; ++j)
          acc[i][j] = fmaf(a[i], b[j], acc[i][j]);
    }
    __syncthreads();
  }
  #pragma unroll
  for (int i = 0; i < 8; ++i) {
    const int mr = tile0 + rg + i;
    #pragma unroll
    for (int j = 0; j < 8; ++j) {
      float v = acc[i][j] + bias[col0 + cg + j];
      if (RELU) v = fmaxf(v, 0.f);
      Cv[(size_t)mr * N + col0 + cg + j] = v;
    }
  }
}

// ---------------------------------------------------------------------------
// transpose+convert: src fp32 [z][R][C] -> fp16 level arrays [z][C][R].
// LEV=2: level-1 stored x2048 (scaled split, matches mgemm epilogue).
// ---------------------------------------------------------------------------
template<int LEV>
__global__ __launch_bounds__(256)
void transp_k(const float* __restrict__ src, unsigned short* __restrict__ d0,
              unsigned short* __restrict__ d1, int R, int C)
{
  __shared__ float tle[32][33];
  const size_t bb = (size_t)blockIdx.z * R * C;
  const int r0 = blockIdx.x * 32, c0 = blockIdx.y * 32;
  const int x = threadIdx.x & 31, y = threadIdx.x >> 5;
  #pragma unroll
  for (int i = 0; i < 32; i += 8)
    tle[y + i][x] = src[bb + (size_t)(r0 + y + i) * C + (c0 + x)];
  __syncthreads();
  #pragma unroll
  for (int i = 0; i < 32; i += 8) {
    const float v = tle[x][y + i];
    const size_t di = bb + (size_t)(c0 + y + i) * R + (r0 + x);
    const unsigned short h0 = f2h(v);
    d0[di] = h0;
    if (LEV > 1) d1[di] = f2h((v - h2f(h0)) * 2048.f);
  }
}

// concat(embP,embR) fp32 -> fp16 hi/lo pair arrays [B][1024]
__global__ __launch_bounds__(256)
void convx_k(const float* __restrict__ eP, const float* __restrict__ eR,
             unsigned short* __restrict__ x0, unsigned short* __restrict__ x1)
{
  const size_t u = (size_t)blockIdx.x * 256 + threadIdx.x;  // 4-elem units
  const size_t row = u >> 8;
  const int c4 = (int)(u & 255) * 4;
  const float* s = (c4 < 512) ? (eP + row * 512 + c4) : (eR + row * 512 + (c4 - 512));
  const float4 v = *(const float4*)s;
  const float vv[4] = {v.x, v.y, v.z, v.w};
  ushort4 h4, l4;
  unsigned short* hp = (unsigned short*)&h4;
  unsigned short* lp = (unsigned short*)&l4;
  #pragma unroll
  for (int j = 0; j < 4; ++j) {
    const unsigned short h0 = f2h(vv[j]);
    hp[j] = h0;
    lp[j] = f2h((vv[j] - h2f(h0)) * 2048.f);
  }
  *(ushort4*)(x0 + row * 1024 + c4) = h4;
  *(ushort4*)(x1 + row * 1024 + c4) = l4;
}

// ---------------------------------------------------------------------------
// In-place LayerNorm + relu over fp16 hi/lo pair rows (fp32 math).
// ---------------------------------------------------------------------------
template<int COLS, bool RELU>
__global__ __launch_bounds__(256)
void ln_pair_k(unsigned short* __restrict__ h0, unsigned short* __restrict__ h1,
               const float* __restrict__ g, const float* __restrict__ b)
{
  constexpr int PER = COLS / 256;
  const size_t row = blockIdx.x;
  unsigned short* r0 = h0 + row * COLS;
  unsigned short* r1 = h1 + row * COLS;
  const int c0 = threadIdx.x * PER;
  float v[PER];
  float s = 0.f, s2 = 0.f;
  #pragma unroll
  for (int i = 0; i < PER; i += 4) {
    const ushort4 a = *(const ushort4*)(r0 + c0 + i);
    const ushort4 c = *(const ushort4*)(r1 + c0 + i);
    v[i+0] = h2f(a.x) + h2f(c.x) * (1.f/2048.f);
    v[i+1] = h2f(a.y) + h2f(c.y) * (1.f/2048.f);
    v[i+2] = h2f(a.z) + h2f(c.z) * (1.f/2048.f);
    v[i+3] = h2f(a.w) + h2f(c.w) * (1.f/2048.f);
  }
  #pragma unroll
  for (int i = 0; i < PER; ++i) { s += v[i]; s2 += v[i] * v[i]; }
  #pragma unroll
  for (int o = 1; o < 64; o <<= 1) { s += __shfl_xor(s, o); s2 += __shfl_xor(s2, o); }
  __shared__ float ss[4], ss2[4];
  const int w = threadIdx.x >> 6;
  if ((threadIdx.x & 63) == 0) { ss[w] = s; ss2[w] = s2; }
  __syncthreads();
  s  = ss[0] + ss[1] + ss[2] + ss[3];
  s2 = ss2[0] + ss2[1] + ss2[2] + ss2[3];
  const float mu = s * (1.f / COLS);
  const float var = s2 * (1.f / COLS) - mu * mu;
  const float rs = rsqrtf(var + 1e-5f);
  #pragma unroll
  for (int i = 0; i < PER; i += 4) {
    ushort4 a4, c4v;
    unsigned short* ap = (unsigned short*)&a4;
    unsigned short* cp = (unsigned short*)&c4v;
    #pragma unroll
    for (int j = 0; j < 4; ++j) {
      const int c = c0 + i + j;
      float y = (v[i+j] - mu) * rs * g[c] + b[c];
      if (RELU) y = fmaxf(y, 0.f);
      const unsigned short hh = f2h(y);
      ap[j] = hh;
      cp[j] = f2h((y - h2f(hh)) * 2048.f);
    }
    *(ushort4*)(r0 + c0 + i) = a4;
    *(ushort4*)(r1 + c0 + i) = c4v;
  }
}

// ---------------------------------------------------------------------------
// In-place LayerNorm over fp32 rows; optionally also emit fp16 mirror.
// ---------------------------------------------------------------------------
template<int COLS, bool RELU, bool F16OUT>
__global__ __launch_bounds__(256)
void ln_k(float* __restrict__ x, const float* __restrict__ g, const float* __restrict__ b,
          unsigned short* __restrict__ x16)
{
  constexpr int PER = COLS / 256;
  const size_t row = blockIdx.x;
  float* xr = x + row * COLS;
  float v[PER];
  float s = 0.f, s2 = 0.f;
  #pragma unroll
  for (int i = 0; i < PER; ++i) {
    v[i] = xr[threadIdx.x + i * 256];
    s += v[i];
    s2 += v[i] * v[i];
  }
  #pragma unroll
  for (int o = 1; o < 64; o <<= 1) { s += __shfl_xor(s, o); s2 += __shfl_xor(s2, o); }
  __shared__ float ss[4], ss2[4];
  const int w = threadIdx.x >> 6;
  if ((threadIdx.x & 63) == 0) { ss[w] = s; ss2[w] = s2; }
  __syncthreads();
  s  = ss[0] + ss[1] + ss[2] + ss[3];
  s2 = ss2[0] + ss2[1] + ss2[2] + ss2[3];
  const float mu = s * (1.f / COLS);
  const float var = s2 * (1.f / COLS) - mu * mu;
  const float rs = rsqrtf(var + 1e-5f);
  #pragma unroll
  for (int i = 0; i < PER; ++i) {
    const int c = threadIdx.x + i * 256;
    float y = (v[i] - mu) * rs * g[c] + b[c];
    if (RELU) y = fmaxf(y, 0.f);
    xr[c] = y;
    if (F16OUT) x16[row * COLS + c] = f2h(y);
  }
}

// ---------------------------------------------------------------------------
// gate: logits = relu-g @ gW2[t] + gb2[t]; top-3 softmax; NO global atomics.
// ---------------------------------------------------------------------------
__global__ __launch_bounds__(256)
void gate_topk_k(const float* __restrict__ g, const float* __restrict__ gW2,
                 const float* __restrict__ gb2, const int* __restrict__ taskPtr,
                 float* __restrict__ gatesOut, int* __restrict__ topkIdx,
                 float* __restrict__ topkW)
{
  const int t = *taskPtr;
  const float* W = gW2 + (size_t)t * 128 * 16;
  const float* bias = gb2 + (size_t)t * 16;
  const int lane = threadIdx.x & 63;
  const int row = blockIdx.x * 4 + (threadIdx.x >> 6);
  const float* gr = g + (size_t)row * 128;
  const int e = lane & 15;
  const int q = lane >> 4;
  float s = 0.f;
  for (int j = q * 32; j < q * 32 + 32; ++j) s = fmaf(gr[j], W[j * 16 + e], s);
  s += __shfl_xor(s, 16);
  s += __shfl_xor(s, 32);
  s += bias[e];
  float logits[16];
  #pragma unroll
  for (int i = 0; i < 16; ++i) logits[i] = __shfl(s, i);
  int i0 = 0; float v0 = logits[0];
  #pragma unroll
  for (int i = 1; i < 16; ++i) if (logits[i] > v0) { v0 = logits[i]; i0 = i; }
  int i1 = -1; float v1 = -3.4e38f;
  #pragma unroll
  for (int i = 0; i < 16; ++i) if (i != i0 && logits[i] > v1) { v1 = logits[i]; i1 = i; }
  int i2 = -1; float v2 = -3.4e38f;
  #pragma unroll
  for (int i = 0; i < 16; ++i) if (i != i0 && i != i1 && logits[i] > v2) { v2 = logits[i]; i2 = i; }
  const float ex1 = expf(v1 - v0);
  const float ex2 = expf(v2 - v0);
  const float inv = 1.f / (1.f + ex1 + ex2);
  const float p0 = inv, p1 = ex1 * inv, p2 = ex2 * inv;
  if (lane < 16) {
    const float gv = (lane == i0) ? p0 : (lane == i1) ? p1 : (lane == i2) ? p2 : 0.f;
    gatesOut[(size_t)row * 16 + lane] = gv;
  }
  if (lane == 0) {
    topkIdx[row * 3 + 0] = i0; topkIdx[row * 3 + 1] = i1; topkIdx[row * 3 + 2] = i2;
    topkW [row * 3 + 0] = p0; topkW [row * 3 + 1] = p1; topkW [row * 3 + 2] = p2;
  }
}

// per-chunk expert histogram (LDS atomics only)
__global__ __launch_bounds__(256)
void hist_k(const int* __restrict__ topkIdx, int* __restrict__ chunkCnt)
{
  __shared__ int lc[NEXP];
  if (threadIdx.x < NEXP) lc[threadIdx.x] = 0;
  __syncthreads();
  const int row = blockIdx.x * 256 + threadIdx.x;
  #pragma unroll
  for (int k = 0; k < 3; ++k) atomicAdd(&lc[topkIdx[row * 3 + k]], 1);
  __syncthreads();
  if (threadIdx.x < NEXP) chunkCnt[blockIdx.x * NEXP + threadIdx.x] = lc[threadIdx.x];
}

// serial scan: counts/offs per expert + per-chunk bases
__global__ void scanB_k(const int* __restrict__ chunkCnt, int* __restrict__ counts,
                        int* __restrict__ offs, int* __restrict__ chunkBase)
{
  if (threadIdx.x == 0) {
    int tot[NEXP];
    for (int e = 0; e < NEXP; ++e) tot[e] = 0;
    for (int c = 0; c < 64; ++c)
      for (int e = 0; e < NEXP; ++e) tot[e] += chunkCnt[c * NEXP + e];
    int a = 0;
    for (int e = 0; e < NEXP; ++e) { offs[e] = a; counts[e] = tot[e]; a += tot[e]; }
    for (int e = 0; e < NEXP; ++e) {
      int b = offs[e];
      for (int c = 0; c < 64; ++c) { chunkBase[c * NEXP + e] = b; b += chunkCnt[c * NEXP + e]; }
    }
  }
}

// fill pair lists: LDS-atomic within-chunk offsets + precomputed chunk base
__global__ __launch_bounds__(256)
void fill2_k(const int* __restrict__ topkIdx, const float* __restrict__ topkW,
             const int* __restrict__ chunkBase, int* __restrict__ pairRow,
             float* __restrict__ pairW, int* __restrict__ rowPos)
{
  __shared__ int lc[NEXP];
  if (threadIdx.x < NEXP) lc[threadIdx.x] = 0;
  __syncthreads();
  const int row = blockIdx.x * 256 + threadIdx.x;
  #pragma unroll
  for (int k = 0; k < 3; ++k) {
    const int e = topkIdx[row * 3 + k];
    const int lofs = atomicAdd(&lc[e], 1);
    const int pos = chunkBase[blockIdx.x * NEXP + e] + lofs;
    pairRow[pos] = row;
    pairW[pos] = topkW[row * 3 + k];
    rowPos[row * 3 + k] = pos;
  }
}

__global__ __launch_bounds__(256)
void mixreduce_k(const unsigned short* __restrict__ eo, const int* __restrict__ rowPos,
                 float* __restrict__ mix)
{
  const size_t row = blockIdx.x;
  const size_t p0 = rowPos[row * 3 + 0];
  const size_t p1 = rowPos[row * 3 + 1];
  const size_t p2 = rowPos[row * 3 + 2];
  for (int c = threadIdx.x; c < EXPSZ; c += 256) {
    mix[row * EXPSZ + c] = h2f(eo[p0 * EXPSZ + c]) + h2f(eo[p1 * EXPSZ + c])
                         + h2f(eo[p2 * EXPSZ + c]);
  }
}

__global__ __launch_bounds__(256)
void tower3_k(const float* __restrict__ t2, const float* __restrict__ tW3,
              const float* __restrict__ tb3, const int* __restrict__ taskPtr,
              float* __restrict__ out)
{
  const int t = *taskPtr;
  const float* w = tW3 + (size_t)t * 128;
  const float bias = tb3[t];
  const int lane = threadIdx.x & 63;
  const int row = blockIdx.x * 4 + (threadIdx.x >> 6);
  const float* x = t2 + (size_t)row * 128;
  float s = fmaf(x[lane], w[lane], x[lane + 64] * w[lane + 64]);
  #pragma unroll
  for (int o = 1; o < 64; o <<= 1) s += __shfl_xor(s, o);
  if (lane == 0) out[row] = 1.f / (1.f + expf(-(s + bias)));
  if (blockIdx.x == 0 && threadIdx.x == 0) out[BATCH] = (float)t;
}

// ---------------------------------------------------------------------------
extern "C" void kernel_launch(void* const* d_in, const int* in_sizes, int n_in,
                              void* d_out, int out_size, void* d_ws, size_t ws_size,
                              hipStream_t stream)
{
  (void)in_sizes; (void)n_in; (void)out_size; (void)ws_size;
  const float* embP  = (const float*)d_in[0];
  const float* embR  = (const float*)d_in[1];
  const float* encW1 = (const float*)d_in[2];
  const float* encB1 = (const float*)d_in[3];
  const float* ln1g  = (const float*)d_in[4];
  const float* ln1b  = (const float*)d_in[5];
  const float* encW2 = (const float*)d_in[6];
  const float* encB2 = (const float*)d_in[7];
  const float* ln2g  = (const float*)d_in[8];
  const float* ln2b  = (const float*)d_in[9];
  const float* gW1   = (const float*)d_in[10];
  const float* gb1   = (const float*)d_in[11];
  const float* gW2   = (const float*)d_in[12];
  const float* gb2   = (const float*)d_in[13];
  const float* We1   = (const float*)d_in[14];
  const float* be1   = (const float*)d_in[15];
  const float* We2   = (const float*)d_in[16];
  const float* be2   = (const float*)d_in[17];
  const float* tW1   = (const float*)d_in[18];
  const float* tb1   = (const float*)d_in[19];
  const float* tW2   = (const float*)d_in[20];
  const float* tb2   = (const float*)d_in[21];
  const float* tW3   = (const float*)d_in[22];
  const float* tb3   = (const float*)d_in[23];
  const int* taskPtr = (const int*)d_in[24];

  float* out = (float*)d_out;
  char* ws = (char*)d_ws;
  const size_t MB = 1ull << 20;

  // Lifetime-aliased workspace (peak ~209 MB):
  //  [0,64):    x0[0,32),x1[32,64) -> feat fp32[0,64) -> e1b[0,48) -> mix[0,32),t1[32,48),t2[48,56)
  //  [64,192):  h0[64,128),h1[128,192) -> We1t0[64,80),We2t0[80,88),feat16[88,120),eob[120,168)
  //  [192,208): W1t0/W1t1 [192,200) -> gbuf[192,200) | W2t0/W2t1 [200,208)
  //  [208,~209): metadata
  unsigned short* x0   = (unsigned short*)(ws);
  unsigned short* x1   = (unsigned short*)(ws + 32 * MB);
  float* feat = (float*)(ws);
  unsigned short* e1b  = (unsigned short*)(ws);
  float* mix  = (float*)(ws);
  float* t1   = (float*)(ws + 32 * MB);
  float* t2v  = (float*)(ws + 48 * MB);
  unsigned short* h0    = (unsigned short*)(ws + 64 * MB);
  unsigned short* h1    = (unsigned short*)(ws + 128 * MB);
  unsigned short* We1t0 = (unsigned short*)(ws + 64 * MB);
  unsigned short* We2t0 = (unsigned short*)(ws + 80 * MB);
  unsigned short* feat16= (unsigned short*)(ws + 88 * MB);
  unsigned short* eob   = (unsigned short*)(ws + 120 * MB);
  unsigned short* W1t0  = (unsigned short*)(ws + 192 * MB);
  unsigned short* W1t1  = (unsigned short*)(ws + 196 * MB);
  unsigned short* W2t0  = (unsigned short*)(ws + 200 * MB);
  unsigned short* W2t1  = (unsigned short*)(ws + 204 * MB);
  float* gbuf = (float*)(ws + 192 * MB);
  char* small = ws + 208 * MB;
  int*   counts    = (int*)  (small);
  int*   offs      = (int*)  (small + 1024);
  int*   chunkCnt  = (int*)  (small + 2048);
  int*   chunkBase = (int*)  (small + 2048 + 4096);
  int*   topkIdx   = (int*)  (small + 16384);
  float* topkW     = (float*)(small + 16384 + 196608);
  int*   pairRow   = (int*)  (small + 16384 + 2 * 196608);
  float* pairW     = (float*)(small + 16384 + 3 * 196608);
  int*   rowPos    = (int*)  (small + 16384 + 4 * 196608);

  const dim3 blk(256, 1, 1);

  // input conversion + encoder GEMM1: h = concat @ W1 + b1 (fp16 split, 3 terms)
  convx_k<<<dim3(16384, 1, 1), blk, 0, stream>>>(embP, embR, x0, x1);
  transp_k<2><<<dim3(DIN/32, DHID/32, 1), blk, 0, stream>>>(encW1, W1t0, W1t1, DIN, DHID);
  mgemm_k<1,0,0,32,DHID/128><<<dim3((BATCH/128)*(DHID/128), 1, 1), blk, 0, stream>>>(
      x0, x1, W1t0, W1t1, encB1, nullptr, h0, h1,
      nullptr, nullptr, nullptr, nullptr, BATCH, DHID, DIN);
  ln_pair_k<DHID, true><<<dim3(BATCH, 1, 1), blk, 0, stream>>>(h0, h1, ln1g, ln1b);

  // encoder GEMM2: feat = h @ W2 + b2 (fp16 split, 3 terms) -> fp32
  transp_k<2><<<dim3(DHID/32, DIN/32, 1), blk, 0, stream>>>(encW2, W2t0, W2t1, DHID, DIN);
  mgemm_k<1,0,3,32,DIN/128><<<dim3((BATCH/128)*(DIN/128), 1, 1), blk, 0, stream>>>(
      h0, h1, W2t0, W2t1, encB2, feat, nullptr, nullptr,
      nullptr, nullptr, nullptr, nullptr, BATCH, DIN, DHID);
  // feat LN: fp32 in-place + fused fp16 mirror for the expert path
  ln_k<DIN, false, true><<<dim3(BATCH, 1, 1), blk, 0, stream>>>(feat, ln2g, ln2b, feat16);

  // gate (fp32 vector path on fp32 feat) — no global atomics anywhere
  gemm32_k<true><<<dim3(BATCH/128, 1, 1), blk, 0, stream>>>(
      feat, gW1, gb1, gbuf, taskPtr, BATCH, 128, DIN);
  gate_topk_k<<<dim3(BATCH/4, 1, 1), blk, 0, stream>>>(
      gbuf, gW2, gb2, taskPtr, out + BATCH + 1, topkIdx, topkW);
  hist_k<<<dim3(BATCH/256, 1, 1), blk, 0, stream>>>(topkIdx, chunkCnt);
  scanB_k<<<dim3(1, 1, 1), dim3(64, 1, 1), 0, stream>>>(chunkCnt, counts, offs, chunkBase);
  fill2_k<<<dim3(BATCH/256, 1, 1), blk, 0, stream>>>(topkIdx, topkW, chunkBase,
                                                     pairRow, pairW, rowPos);

  // expert weights in fp16 (h region free now)
  transp_k<1><<<dim3(DIN/32, EXPSZ/32, NEXP), blk, 0, stream>>>(We1, We1t0, nullptr, DIN, EXPSZ);
  transp_k<1><<<dim3(EXPSZ/32, EXPSZ/32, NEXP), blk, 0, stream>>>(We2, We2t0, nullptr, EXPSZ, EXPSZ);

  // expert GEMM1: e1 = relu(feat16[pairRow] @ We1[e] + be1)  (plain fp16, gl2lds gather)
  mgemm_k<0,1,1,64,EXPSZ/128><<<dim3((BATCH/128)*(EXPSZ/128), 1, NEXP), blk, 0, stream>>>(
      feat16, nullptr, We1t0, nullptr, be1, nullptr, e1b, nullptr,
      pairRow, nullptr, counts, offs, NPAIR, EXPSZ, DIN);
  // expert GEMM2: eo = w_p * (e1 @ We2[e] + be2)  (plain fp16)
  mgemm_k<0,2,2,64,EXPSZ/128><<<dim3((BATCH/128)*(EXPSZ/128), 1, NEXP), blk, 0, stream>>>(
      e1b, nullptr, We2t0, nullptr, be2, nullptr, eob, nullptr,
      nullptr, pairW, counts, offs, NPAIR, EXPSZ, EXPSZ);
  mixreduce_k<<<dim3(BATCH, 1, 1), blk, 0, stream>>>(eob, rowPos, mix);

  // towers (fp32)
  gemm32_k<true><<<dim3(BATCH/128, 2, 1), blk, 0, stream>>>(
      mix, tW1, tb1, t1, taskPtr, BATCH, 256, EXPSZ);
  gemm32_k<true><<<dim3(BATCH/128, 1, 1), blk, 0, stream>>>(
      t1, tW2, tb2, t2v, taskPtr, BATCH, 128, 256);
  tower3_k<<<dim3(BATCH/4, 1, 1), blk, 0, stream>>>(t2v, tW3, tb3, taskPtr, out);
}

// Round 10
// 1310.344 us; speedup vs baseline: 1.3727x; 1.3727x over previous
//
#include <hip/hip_runtime.h>

typedef __attribute__((ext_vector_type(8))) _Float16 f16x8;
typedef __attribute__((ext_vector_type(4))) float f32x4;

#define DEVINL __device__ __forceinline__

constexpr int BATCH = 16384;
constexpr int DIN   = 1024;
constexpr int DHID  = 2048;
constexpr int NEXP  = 16;
constexpr int EXPSZ = 512;
constexpr int NPAIR = BATCH * 3;

DEVINL unsigned short f2h(float v) {
  _Float16 h = (_Float16)v;
  return __builtin_bit_cast(unsigned short, h);
}
DEVINL float h2f(unsigned short u) {
  return (float)__builtin_bit_cast(_Float16, u);
}

DEVINL void gl2lds(const unsigned short* src, char* ldst) {
  __builtin_amdgcn_global_load_lds((const __attribute__((address_space(1))) void*)src,
                                   (__attribute__((address_space(3))) void*)ldst, 16, 0, 0);
}

// ---------------------------------------------------------------------------
// fp16 split-MFMA GEMM, 128x128 tile, 4 waves (2x2 of 64x64), 16x16x32 f16.
// Operands are fp16 level arrays staged via global_load_lds (fragment-
// contiguous LDS: unit u (16B) = g*128 + row -> elems [row][kt+g*8..+7]).
// 1D grid (x = NXT*NYT tiles, z = expert). Tile mapping: row-tiles are
// ROUND-ROBINED across XCDs (xcd = bid&7 owns row-tiles xcd, xcd+8, ...)
// and the NYT col-tiles of a row-tile are consecutive within the XCD.
// -> load-balanced under early-exit (expert kernels: only counts[e] rows
//    alive) AND the A-panel is fetched into one XCD's L2 once per row-tile
//    and reused across all col-tiles. Bijective for NXT%8==0: speed-only.
// SPLIT=1: v = c0 + c1/2048 (c1 stored x2048). 3 MFMA terms; result =
//   acc + acc2/2048. SPLIT=0: plain fp16.
// AMODE: 0 linear A rows; 1 gather A rows via pairRow; 2 pair-linear A rows.
// EPI:   0 = +bias -> fp16 hi/lo pair; 1 = +bias,relu -> fp16;
//        2 = +bias,*pairW -> fp16; 3 = +bias -> fp32.
// ---------------------------------------------------------------------------
template<int SPLIT, int AMODE, int EPI, int BK, int NYT>
__global__ __launch_bounds__(256, SPLIT ? 2 : 3)
void mgemm_k(const unsigned short* __restrict__ A0p,
             const unsigned short* __restrict__ A1p,
             const unsigned short* __restrict__ B0p,
             const unsigned short* __restrict__ B1p,
             const float* __restrict__ biasb,
             float* __restrict__ Cf, unsigned short* __restrict__ Cb0,
             unsigned short* __restrict__ Cb1,
             const int* __restrict__ pairRow, const float* __restrict__ pairW,
             const int* __restrict__ counts, const int* __restrict__ offs,
             int M, int N, int K)
{
  constexpr int KG = BK / 8;
  constexpr int UNITS = 128 * KG;
  constexpr int ISS = UNITS / 256;
  constexpr int NKK = BK / 32;
  constexpr int NARR = SPLIT ? 4 : 2;
  constexpr bool EXPERT = (AMODE == 1 || AMODE == 2);
  __shared__ char smem[NARR * UNITS * 16];
  char* sA0 = smem;
  char* sA1 = smem + UNITS * 16;                    // iff SPLIT
  char* sB0 = smem + (SPLIT ? 2 : 1) * UNITS * 16;
  char* sB1 = smem + 3 * UNITS * 16;                // iff SPLIT

  int Mloc = M, rowBase = 0;
  const unsigned short* b0 = B0p;
  const unsigned short* b1 = B1p;
  const float* bias = biasb;
  if (EXPERT) {
    const int e = blockIdx.z;
    Mloc = counts[e];
    rowBase = offs[e];
    const size_t eo = (size_t)e * (size_t)K * N;
    b0 = B0p + eo;
    if (SPLIT) b1 = B1p + eo;
    bias = biasb + (size_t)e * N;
  }

  // round-robin row-tiles over XCDs; col-tiles consecutive within XCD
  const int xcd = (int)blockIdx.x & 7;
  const int j   = (int)blockIdx.x >> 3;
  const int tile0 = (xcd + 8 * (j / NYT)) * 128;
  const int col0  = (j % NYT) * 128;
  if (tile0 >= Mloc) return;

  const int tid = threadIdx.x;
  const int lane = tid & 63;
  const int wr = ((tid >> 6) >> 1) * 64;
  const int wc = ((tid >> 6) & 1) * 64;
  const int l15 = lane & 15;
  const int lg = lane >> 4;

  // per-thread staging row (fixed across K)
  const int srow = tid & 127;
  size_t aoff;
  if (AMODE == 0) {
    aoff = (size_t)(tile0 + srow) * K;
  } else if (AMODE == 1) {
    int p = rowBase + tile0 + srow; p = p < NPAIR - 1 ? p : NPAIR - 1;
    aoff = (size_t)pairRow[p] * K;
  } else {
    int p = rowBase + tile0 + srow; p = p < NPAIR - 1 ? p : NPAIR - 1;
    aoff = (size_t)p * K;
  }
  const size_t boff = (size_t)(col0 + srow) * K;

  f32x4 acc[4][4];
  f32x4 acc2[4][4];
  #pragma unroll
  for (int m = 0; m < 4; ++m)
    #pragma unroll
    for (int n = 0; n < 4; ++n) {
      acc[m][n] = f32x4{0.f, 0.f, 0.f, 0.f};
      if (SPLIT) acc2[m][n] = f32x4{0.f, 0.f, 0.f, 0.f};
    }

  for (int kt = 0; kt < K; kt += BK) {
    #pragma unroll
    for (int it = 0; it < ISS; ++it) {
      const int uo = (it * 256 + (tid & 192)) * 16;   // wave-uniform LDS base
      const int ko = kt + (it * 2 + (tid >> 7)) * 8;
      gl2lds(A0p + aoff + ko, sA0 + uo);
      if (SPLIT) gl2lds(A1p + aoff + ko, sA1 + uo);
      gl2lds(b0 + boff + ko, sB0 + uo);
      if (SPLIT) gl2lds(b1 + boff + ko, sB1 + uo);
    }
    __syncthreads();
    #pragma unroll
    for (int kk = 0; kk < NKK; ++kk) {
      const int g = kk * 4 + lg;
      f16x8 b0f[4], b1f[4];
      #pragma unroll
      for (int n = 0; n < 4; ++n) {
        const size_t off = (size_t)(g * 128 + wc + n * 16 + l15) * 16;
        b0f[n] = *(const f16x8*)(sB0 + off);
        if (SPLIT) b1f[n] = *(const f16x8*)(sB1 + off);
      }
      #pragma unroll
      for (int m = 0; m < 4; ++m) {
        const size_t ao = (size_t)(g * 128 + wr + m * 16 + l15) * 16;
        const f16x8 a0 = *(const f16x8*)(sA0 + ao);
        f16x8 a1;
        if (SPLIT) a1 = *(const f16x8*)(sA1 + ao);
        #pragma unroll
        for (int n = 0; n < 4; ++n) {
          if (SPLIT) {
            acc2[m][n] = __builtin_amdgcn_mfma_f32_16x16x32_f16(a1, b0f[n], acc2[m][n], 0, 0, 0);
            acc2[m][n] = __builtin_amdgcn_mfma_f32_16x16x32_f16(a0, b1f[n], acc2[m][n], 0, 0, 0);
          }
          acc[m][n] = __builtin_amdgcn_mfma_f32_16x16x32_f16(a0, b0f[n], acc[m][n], 0, 0, 0);
        }
      }
    }
    __syncthreads();
  }

  // epilogue. C/D mapping: col = lane&15, row = (lane>>4)*4 + j  [m89-verified]
  #pragma unroll
  for (int n = 0; n < 4; ++n) {
    const int cn = col0 + wc + n * 16 + l15;
    const float bv = bias[cn];
    #pragma unroll
    for (int m = 0; m < 4; ++m) {
      const int r0 = wr + m * 16 + ((lane >> 4) << 2);
      #pragma unroll
      for (int jj = 0; jj < 4; ++jj) {
        const int rm = tile0 + r0 + jj;
        if (EXPERT && rm >= Mloc) continue;
        float v = acc[m][n][jj];
        if (SPLIT) v += acc2[m][n][jj] * (1.f / 2048.f);
        v += bv;
        const size_t ci = (size_t)(EXPERT ? (rowBase + rm) : rm) * N + cn;
        if (EPI == 0) {
          const unsigned short h0 = f2h(v);
          Cb0[ci] = h0;
          Cb1[ci] = f2h((v - h2f(h0)) * 2048.f);
        } else if (EPI == 1) {
          Cb0[ci] = f2h(fmaxf(v, 0.f));
        } else if (EPI == 2) {
          Cb0[ci] = f2h(v * pairW[rowBase + rm]);
        } else {
          Cf[ci] = v;
        }
      }
    }
  }
}

// ---------------------------------------------------------------------------
// fp32 vector GEMM (gate + towers). C = relu(A@B[t] + bias[t]), fp32.
// ---------------------------------------------------------------------------
template<bool RELU>
__global__ __launch_bounds__(256, 2)
void gemm32_k(const float* __restrict__ Av, const float* __restrict__ Bb,
              const float* __restrict__ biasb, float* __restrict__ Cv,
              const int* __restrict__ taskPtr, int M, int N, int K)
{
  __shared__ float As[16][128];
  __shared__ float Bs[16][128];
  const int t = *taskPtr;
  const float* Bw = Bb + (size_t)t * K * N;
  const float* bias = biasb + (size_t)t * N;
  const int tile0 = blockIdx.x * 128;
  const int col0 = blockIdx.y * 128;
  const int tid = threadIdx.x;
  const int am = tid >> 1, ak = (tid & 1) * 8;
  const int bk = tid >> 4, bn = (tid & 15) * 8;
  const int rg = (tid >> 4) * 8, cg = (tid & 15) * 8;
  const float* aptr = Av + (size_t)(tile0 + am) * K;

  float acc[8][8];
  #pragma unroll
  for (int i = 0; i < 8; ++i)
    #pragma unroll
    for (int j = 0; j < 8; ++j) acc[i][j] = 0.f;

  for (int kt = 0; kt < K; kt += 16) {
    {
      const float* src = aptr + kt + ak;
      float4 x0 = *reinterpret_cast<const float4*>(src);
      float4 x1 = *reinterpret_cast<const float4*>(src + 4);
      As[ak+0][am]=x0.x; As[ak+1][am]=x0.y; As[ak+2][am]=x0.z; As[ak+3][am]=x0.w;
      As[ak+4][am]=x1.x; As[ak+5][am]=x1.y; As[ak+6][am]=x1.z; As[ak+7][am]=x1.w;
    }
    {
      const float* bsrc = Bw + (size_t)(kt + bk) * N + (col0 + bn);
      float4 b0 = *reinterpret_cast<const float4*>(bsrc);
      float4 b1 = *reinterpret_cast<const float4*>(bsrc + 4);
      Bs[bk][bn+0]=b0.x; Bs[bk][bn+1]=b0.y; Bs[bk][bn+2]=b0.z; Bs[bk][bn+3]=b0.w;
      Bs[bk][bn+4]=b1.x; Bs[bk][bn+5]=b1.y; Bs[bk][bn+6]=b1.z; Bs[bk][bn+7]=b1.w;
    }
    __syncthreads();
    #pragma unroll
    for (int k = 0; k < 16; ++k) {
      float4 a0 = *reinterpret_cast<const float4*>(&As[k][rg]);
      float4 a1 = *reinterpret_cast<const float4*>(&As[k][rg + 4]);
      float4 c0 = *reinterpret_cast<const float4*>(&Bs[k][cg]);
      float4 c1 = *reinterpret_cast<const float4*>(&Bs[k][cg + 4]);
      const float a[8] = {a0.x,a0.y,a0.z,a0.w,a1.x,a1.y,a1.z,a1.w};
      const float b[8] = {c0.x,c0.y,c0.z,c0.w,c1.x,c1.y,c1.z,c1.w};
      #pragma unroll
      for (int i = 0; i < 8; ++i)
        #pragma unroll
        for (int j = 0; j < 8; ++j)
          acc[i][j] = fmaf(a[i], b[j], acc[i][j]);
    }
    __syncthreads();
  }
  #pragma unroll
  for (int i = 0; i < 8; ++i) {
    const int mr = tile0 + rg + i;
    #pragma unroll
    for (int j = 0; j < 8; ++j) {
      float v = acc[i][j] + bias[col0 + cg + j];
      if (RELU) v = fmaxf(v, 0.f);
      Cv[(size_t)mr * N + col0 + cg + j] = v;
    }
  }
}

// ---------------------------------------------------------------------------
// transpose+convert: src fp32 [z][R][C] -> fp16 level arrays [z][C][R].
// LEV=2: level-1 stored x2048 (scaled split, matches mgemm epilogue).
// ---------------------------------------------------------------------------
template<int LEV>
__global__ __launch_bounds__(256)
void transp_k(const float* __restrict__ src, unsigned short* __restrict__ d0,
              unsigned short* __restrict__ d1, int R, int C)
{
  __shared__ float tle[32][33];
  const size_t bb = (size_t)blockIdx.z * R * C;
  const int r0 = blockIdx.x * 32, c0 = blockIdx.y * 32;
  const int x = threadIdx.x & 31, y = threadIdx.x >> 5;
  #pragma unroll
  for (int i = 0; i < 32; i += 8)
    tle[y + i][x] = src[bb + (size_t)(r0 + y + i) * C + (c0 + x)];
  __syncthreads();
  #pragma unroll
  for (int i = 0; i < 32; i += 8) {
    const float v = tle[x][y + i];
    const size_t di = bb + (size_t)(c0 + y + i) * R + (r0 + x);
    const unsigned short h0 = f2h(v);
    d0[di] = h0;
    if (LEV > 1) d1[di] = f2h((v - h2f(h0)) * 2048.f);
  }
}

// concat(embP,embR) fp32 -> fp16 hi/lo pair arrays [B][1024]
__global__ __launch_bounds__(256)
void convx_k(const float* __restrict__ eP, const float* __restrict__ eR,
             unsigned short* __restrict__ x0, unsigned short* __restrict__ x1)
{
  const size_t u = (size_t)blockIdx.x * 256 + threadIdx.x;  // 4-elem units
  const size_t row = u >> 8;
  const int c4 = (int)(u & 255) * 4;
  const float* s = (c4 < 512) ? (eP + row * 512 + c4) : (eR + row * 512 + (c4 - 512));
  const float4 v = *(const float4*)s;
  const float vv[4] = {v.x, v.y, v.z, v.w};
  ushort4 h4, l4;
  unsigned short* hp = (unsigned short*)&h4;
  unsigned short* lp = (unsigned short*)&l4;
  #pragma unroll
  for (int j = 0; j < 4; ++j) {
    const unsigned short h0 = f2h(vv[j]);
    hp[j] = h0;
    lp[j] = f2h((vv[j] - h2f(h0)) * 2048.f);
  }
  *(ushort4*)(x0 + row * 1024 + c4) = h4;
  *(ushort4*)(x1 + row * 1024 + c4) = l4;
}

// ---------------------------------------------------------------------------
// In-place LayerNorm + relu over fp16 hi/lo pair rows (fp32 math).
// ---------------------------------------------------------------------------
template<int COLS, bool RELU>
__global__ __launch_bounds__(256)
void ln_pair_k(unsigned short* __restrict__ h0, unsigned short* __restrict__ h1,
               const float* __restrict__ g, const float* __restrict__ b)
{
  constexpr int PER = COLS / 256;
  const size_t row = blockIdx.x;
  unsigned short* r0 = h0 + row * COLS;
  unsigned short* r1 = h1 + row * COLS;
  const int c0 = threadIdx.x * PER;
  float v[PER];
  float s = 0.f, s2 = 0.f;
  #pragma unroll
  for (int i = 0; i < PER; i += 4) {
    const ushort4 a = *(const ushort4*)(r0 + c0 + i);
    const ushort4 c = *(const ushort4*)(r1 + c0 + i);
    v[i+0] = h2f(a.x) + h2f(c.x) * (1.f/2048.f);
    v[i+1] = h2f(a.y) + h2f(c.y) * (1.f/2048.f);
    v[i+2] = h2f(a.z) + h2f(c.z) * (1.f/2048.f);
    v[i+3] = h2f(a.w) + h2f(c.w) * (1.f/2048.f);
  }
  #pragma unroll
  for (int i = 0; i < PER; ++i) { s += v[i]; s2 += v[i] * v[i]; }
  #pragma unroll
  for (int o = 1; o < 64; o <<= 1) { s += __shfl_xor(s, o); s2 += __shfl_xor(s2, o); }
  __shared__ float ss[4], ss2[4];
  const int w = threadIdx.x >> 6;
  if ((threadIdx.x & 63) == 0) { ss[w] = s; ss2[w] = s2; }
  __syncthreads();
  s  = ss[0] + ss[1] + ss[2] + ss[3];
  s2 = ss2[0] + ss2[1] + ss2[2] + ss2[3];
  const float mu = s * (1.f / COLS);
  const float var = s2 * (1.f / COLS) - mu * mu;
  const float rs = rsqrtf(var + 1e-5f);
  #pragma unroll
  for (int i = 0; i < PER; i += 4) {
    ushort4 a4, c4v;
    unsigned short* ap = (unsigned short*)&a4;
    unsigned short* cp = (unsigned short*)&c4v;
    #pragma unroll
    for (int j = 0; j < 4; ++j) {
      const int c = c0 + i + j;
      float y = (v[i+j] - mu) * rs * g[c] + b[c];
      if (RELU) y = fmaxf(y, 0.f);
      const unsigned short hh = f2h(y);
      ap[j] = hh;
      cp[j] = f2h((y - h2f(hh)) * 2048.f);
    }
    *(ushort4*)(r0 + c0 + i) = a4;
    *(ushort4*)(r1 + c0 + i) = c4v;
  }
}

// ---------------------------------------------------------------------------
// In-place LayerNorm over fp32 rows; optionally also emit fp16 mirror.
// ---------------------------------------------------------------------------
template<int COLS, bool RELU, bool F16OUT>
__global__ __launch_bounds__(256)
void ln_k(float* __restrict__ x, const float* __restrict__ g, const float* __restrict__ b,
          unsigned short* __restrict__ x16)
{
  constexpr int PER = COLS / 256;
  const size_t row = blockIdx.x;
  float* xr = x + row * COLS;
  float v[PER];
  float s = 0.f, s2 = 0.f;
  #pragma unroll
  for (int i = 0; i < PER; ++i) {
    v[i] = xr[threadIdx.x + i * 256];
    s += v[i];
    s2 += v[i] * v[i];
  }
  #pragma unroll
  for (int o = 1; o < 64; o <<= 1) { s += __shfl_xor(s, o); s2 += __shfl_xor(s2, o); }
  __shared__ float ss[4], ss2[4];
  const int w = threadIdx.x >> 6;
  if ((threadIdx.x & 63) == 0) { ss[w] = s; ss2[w] = s2; }
  __syncthreads();
  s  = ss[0] + ss[1] + ss[2] + ss[3];
  s2 = ss2[0] + ss2[1] + ss2[2] + ss2[3];
  const float mu = s * (1.f / COLS);
  const float var = s2 * (1.f / COLS) - mu * mu;
  const float rs = rsqrtf(var + 1e-5f);
  #pragma unroll
  for (int i = 0; i < PER; ++i) {
    const int c = threadIdx.x + i * 256;
    float y = (v[i] - mu) * rs * g[c] + b[c];
    if (RELU) y = fmaxf(y, 0.f);
    xr[c] = y;
    if (F16OUT) x16[row * COLS + c] = f2h(y);
  }
}

// ---------------------------------------------------------------------------
// gate: logits = relu-g @ gW2[t] + gb2[t]; top-3 softmax; NO global atomics.
// ---------------------------------------------------------------------------
__global__ __launch_bounds__(256)
void gate_topk_k(const float* __restrict__ g, const float* __restrict__ gW2,
                 const float* __restrict__ gb2, const int* __restrict__ taskPtr,
                 float* __restrict__ gatesOut, int* __restrict__ topkIdx,
                 float* __restrict__ topkW)
{
  const int t = *taskPtr;
  const float* W = gW2 + (size_t)t * 128 * 16;
  const float* bias = gb2 + (size_t)t * 16;
  const int lane = threadIdx.x & 63;
  const int row = blockIdx.x * 4 + (threadIdx.x >> 6);
  const float* gr = g + (size_t)row * 128;
  const int e = lane & 15;
  const int q = lane >> 4;
  float s = 0.f;
  for (int j = q * 32; j < q * 32 + 32; ++j) s = fmaf(gr[j], W[j * 16 + e], s);
  s += __shfl_xor(s, 16);
  s += __shfl_xor(s, 32);
  s += bias[e];
  float logits[16];
  #pragma unroll
  for (int i = 0; i < 16; ++i) logits[i] = __shfl(s, i);
  int i0 = 0; float v0 = logits[0];
  #pragma unroll
  for (int i = 1; i < 16; ++i) if (logits[i] > v0) { v0 = logits[i]; i0 = i; }
  int i1 = -1; float v1 = -3.4e38f;
  #pragma unroll
  for (int i = 0; i < 16; ++i) if (i != i0 && logits[i] > v1) { v1 = logits[i]; i1 = i; }
  int i2 = -1; float v2 = -3.4e38f;
  #pragma unroll
  for (int i = 0; i < 16; ++i) if (i != i0 && i != i1 && logits[i] > v2) { v2 = logits[i]; i2 = i; }
  const float ex1 = expf(v1 - v0);
  const float ex2 = expf(v2 - v0);
  const float inv = 1.f / (1.f + ex1 + ex2);
  const float p0 = inv, p1 = ex1 * inv, p2 = ex2 * inv;
  if (lane < 16) {
    const float gv = (lane == i0) ? p0 : (lane == i1) ? p1 : (lane == i2) ? p2 : 0.f;
    gatesOut[(size_t)row * 16 + lane] = gv;
  }
  if (lane == 0) {
    topkIdx[row * 3 + 0] = i0; topkIdx[row * 3 + 1] = i1; topkIdx[row * 3 + 2] = i2;
    topkW [row * 3 + 0] = p0; topkW [row * 3 + 1] = p1; topkW [row * 3 + 2] = p2;
  }
}

// per-chunk expert histogram (LDS atomics only)
__global__ __launch_bounds__(256)
void hist_k(const int* __restrict__ topkIdx, int* __restrict__ chunkCnt)
{
  __shared__ int lc[NEXP];
  if (threadIdx.x < NEXP) lc[threadIdx.x] = 0;
  __syncthreads();
  const int row = blockIdx.x * 256 + threadIdx.x;
  #pragma unroll
  for (int k = 0; k < 3; ++k) atomicAdd(&lc[topkIdx[row * 3 + k]], 1);
  __syncthreads();
  if (threadIdx.x < NEXP) chunkCnt[blockIdx.x * NEXP + threadIdx.x] = lc[threadIdx.x];
}

// serial scan: counts/offs per expert + per-chunk bases
__global__ void scanB_k(const int* __restrict__ chunkCnt, int* __restrict__ counts,
                        int* __restrict__ offs, int* __restrict__ chunkBase)
{
  if (threadIdx.x == 0) {
    int tot[NEXP];
    for (int e = 0; e < NEXP; ++e) tot[e] = 0;
    for (int c = 0; c < 64; ++c)
      for (int e = 0; e < NEXP; ++e) tot[e] += chunkCnt[c * NEXP + e];
    int a = 0;
    for (int e = 0; e < NEXP; ++e) { offs[e] = a; counts[e] = tot[e]; a += tot[e]; }
    for (int e = 0; e < NEXP; ++e) {
      int b = offs[e];
      for (int c = 0; c < 64; ++c) { chunkBase[c * NEXP + e] = b; b += chunkCnt[c * NEXP + e]; }
    }
  }
}

// fill pair lists: LDS-atomic within-chunk offsets + precomputed chunk base
__global__ __launch_bounds__(256)
void fill2_k(const int* __restrict__ topkIdx, const float* __restrict__ topkW,
             const int* __restrict__ chunkBase, int* __restrict__ pairRow,
             float* __restrict__ pairW, int* __restrict__ rowPos)
{
  __shared__ int lc[NEXP];
  if (threadIdx.x < NEXP) lc[threadIdx.x] = 0;
  __syncthreads();
  const int row = blockIdx.x * 256 + threadIdx.x;
  #pragma unroll
  for (int k = 0; k < 3; ++k) {
    const int e = topkIdx[row * 3 + k];
    const int lofs = atomicAdd(&lc[e], 1);
    const int pos = chunkBase[blockIdx.x * NEXP + e] + lofs;
    pairRow[pos] = row;
    pairW[pos] = topkW[row * 3 + k];
    rowPos[row * 3 + k] = pos;
  }
}

__global__ __launch_bounds__(256)
void mixreduce_k(const unsigned short* __restrict__ eo, const int* __restrict__ rowPos,
                 float* __restrict__ mix)
{
  const size_t row = blockIdx.x;
  const size_t p0 = rowPos[row * 3 + 0];
  const size_t p1 = rowPos[row * 3 + 1];
  const size_t p2 = rowPos[row * 3 + 2];
  for (int c = threadIdx.x; c < EXPSZ; c += 256) {
    mix[row * EXPSZ + c] = h2f(eo[p0 * EXPSZ + c]) + h2f(eo[p1 * EXPSZ + c])
                         + h2f(eo[p2 * EXPSZ + c]);
  }
}

__global__ __launch_bounds__(256)
void tower3_k(const float* __restrict__ t2, const float* __restrict__ tW3,
              const float* __restrict__ tb3, const int* __restrict__ taskPtr,
              float* __restrict__ out)
{
  const int t = *taskPtr;
  const float* w = tW3 + (size_t)t * 128;
  const float bias = tb3[t];
  const int lane = threadIdx.x & 63;
  const int row = blockIdx.x * 4 + (threadIdx.x >> 6);
  const float* x = t2 + (size_t)row * 128;
  float s = fmaf(x[lane], w[lane], x[lane + 64] * w[lane + 64]);
  #pragma unroll
  for (int o = 1; o < 64; o <<= 1) s += __shfl_xor(s, o);
  if (lane == 0) out[row] = 1.f / (1.f + expf(-(s + bias)));
  if (blockIdx.x == 0 && threadIdx.x == 0) out[BATCH] = (float)t;
}

// ---------------------------------------------------------------------------
extern "C" void kernel_launch(void* const* d_in, const int* in_sizes, int n_in,
                              void* d_out, int out_size, void* d_ws, size_t ws_size,
                              hipStream_t stream)
{
  (void)in_sizes; (void)n_in; (void)out_size; (void)ws_size;
  const float* embP  = (const float*)d_in[0];
  const float* embR  = (const float*)d_in[1];
  const float* encW1 = (const float*)d_in[2];
  const float* encB1 = (const float*)d_in[3];
  const float* ln1g  = (const float*)d_in[4];
  const float* ln1b  = (const float*)d_in[5];
  const float* encW2 = (const float*)d_in[6];
  const float* encB2 = (const float*)d_in[7];
  const float* ln2g  = (const float*)d_in[8];
  const float* ln2b  = (const float*)d_in[9];
  const float* gW1   = (const float*)d_in[10];
  const float* gb1   = (const float*)d_in[11];
  const float* gW2   = (const float*)d_in[12];
  const float* gb2   = (const float*)d_in[13];
  const float* We1   = (const float*)d_in[14];
  const float* be1   = (const float*)d_in[15];
  const float* We2   = (const float*)d_in[16];
  const float* be2   = (const float*)d_in[17];
  const float* tW1   = (const float*)d_in[18];
  const float* tb1   = (const float*)d_in[19];
  const float* tW2   = (const float*)d_in[20];
  const float* tb2   = (const float*)d_in[21];
  const float* tW3   = (const float*)d_in[22];
  const float* tb3   = (const float*)d_in[23];
  const int* taskPtr = (const int*)d_in[24];

  float* out = (float*)d_out;
  char* ws = (char*)d_ws;
  const size_t MB = 1ull << 20;

  // Lifetime-aliased workspace (peak ~209 MB):
  //  [0,64):    x0[0,32),x1[32,64) -> feat fp32[0,64) -> e1b[0,48) -> mix[0,32),t1[32,48),t2[48,56)
  //  [64,192):  h0[64,128),h1[128,192) -> We1t0[64,80),We2t0[80,88),feat16[88,120),eob[120,168)
  //  [192,208): W1t0/W1t1 [192,200) -> gbuf[192,200) | W2t0/W2t1 [200,208)
  //  [208,~209): metadata
  unsigned short* x0   = (unsigned short*)(ws);
  unsigned short* x1   = (unsigned short*)(ws + 32 * MB);
  float* feat = (float*)(ws);
  unsigned short* e1b  = (unsigned short*)(ws);
  float* mix  = (float*)(ws);
  float* t1   = (float*)(ws + 32 * MB);
  float* t2v  = (float*)(ws + 48 * MB);
  unsigned short* h0    = (unsigned short*)(ws + 64 * MB);
  unsigned short* h1    = (unsigned short*)(ws + 128 * MB);
  unsigned short* We1t0 = (unsigned short*)(ws + 64 * MB);
  unsigned short* We2t0 = (unsigned short*)(ws + 80 * MB);
  unsigned short* feat16= (unsigned short*)(ws + 88 * MB);
  unsigned short* eob   = (unsigned short*)(ws + 120 * MB);
  unsigned short* W1t0  = (unsigned short*)(ws + 192 * MB);
  unsigned short* W1t1  = (unsigned short*)(ws + 196 * MB);
  unsigned short* W2t0  = (unsigned short*)(ws + 200 * MB);
  unsigned short* W2t1  = (unsigned short*)(ws + 204 * MB);
  float* gbuf = (float*)(ws + 192 * MB);
  char* small = ws + 208 * MB;
  int*   counts    = (int*)  (small);
  int*   offs      = (int*)  (small + 1024);
  int*   chunkCnt  = (int*)  (small + 2048);
  int*   chunkBase = (int*)  (small + 2048 + 4096);
  int*   topkIdx   = (int*)  (small + 16384);
  float* topkW     = (float*)(small + 16384 + 196608);
  int*   pairRow   = (int*)  (small + 16384 + 2 * 196608);
  float* pairW     = (float*)(small + 16384 + 3 * 196608);
  int*   rowPos    = (int*)  (small + 16384 + 4 * 196608);

  const dim3 blk(256, 1, 1);

  // input conversion + encoder GEMM1: h = concat @ W1 + b1 (fp16 split, 3 terms)
  convx_k<<<dim3(16384, 1, 1), blk, 0, stream>>>(embP, embR, x0, x1);
  transp_k<2><<<dim3(DIN/32, DHID/32, 1), blk, 0, stream>>>(encW1, W1t0, W1t1, DIN, DHID);
  mgemm_k<1,0,0,32,DHID/128><<<dim3((BATCH/128)*(DHID/128), 1, 1), blk, 0, stream>>>(
      x0, x1, W1t0, W1t1, encB1, nullptr, h0, h1,
      nullptr, nullptr, nullptr, nullptr, BATCH, DHID, DIN);
  ln_pair_k<DHID, true><<<dim3(BATCH, 1, 1), blk, 0, stream>>>(h0, h1, ln1g, ln1b);

  // encoder GEMM2: feat = h @ W2 + b2 (fp16 split, 3 terms) -> fp32
  transp_k<2><<<dim3(DHID/32, DIN/32, 1), blk, 0, stream>>>(encW2, W2t0, W2t1, DHID, DIN);
  mgemm_k<1,0,3,32,DIN/128><<<dim3((BATCH/128)*(DIN/128), 1, 1), blk, 0, stream>>>(
      h0, h1, W2t0, W2t1, encB2, feat, nullptr, nullptr,
      nullptr, nullptr, nullptr, nullptr, BATCH, DIN, DHID);
  // feat LN: fp32 in-place + fused fp16 mirror for the expert path
  ln_k<DIN, false, true><<<dim3(BATCH, 1, 1), blk, 0, stream>>>(feat, ln2g, ln2b, feat16);

  // gate (fp32 vector path on fp32 feat) — no global atomics anywhere
  gemm32_k<true><<<dim3(BATCH/128, 1, 1), blk, 0, stream>>>(
      feat, gW1, gb1, gbuf, taskPtr, BATCH, 128, DIN);
  gate_topk_k<<<dim3(BATCH/4, 1, 1), blk, 0, stream>>>(
      gbuf, gW2, gb2, taskPtr, out + BATCH + 1, topkIdx, topkW);
  hist_k<<<dim3(BATCH/256, 1, 1), blk, 0, stream>>>(topkIdx, chunkCnt);
  scanB_k<<<dim3(1, 1, 1), dim3(64, 1, 1), 0, stream>>>(chunkCnt, counts, offs, chunkBase);
  fill2_k<<<dim3(BATCH/256, 1, 1), blk, 0, stream>>>(topkIdx, topkW, chunkBase,
                                                     pairRow, pairW, rowPos);

  // expert weights in fp16 (h region free now)
  transp_k<1><<<dim3(DIN/32, EXPSZ/32, NEXP), blk, 0, stream>>>(We1, We1t0, nullptr, DIN, EXPSZ);
  transp_k<1><<<dim3(EXPSZ/32, EXPSZ/32, NEXP), blk, 0, stream>>>(We2, We2t0, nullptr, EXPSZ, EXPSZ);

  // expert GEMM1: e1 = relu(feat16[pairRow] @ We1[e] + be1)  (plain fp16, gl2lds gather)
  mgemm_k<0,1,1,64,EXPSZ/128><<<dim3((BATCH/128)*(EXPSZ/128), 1, NEXP), blk, 0, stream>>>(
      feat16, nullptr, We1t0, nullptr, be1, nullptr, e1b, nullptr,
      pairRow, nullptr, counts, offs, NPAIR, EXPSZ, DIN);
  // expert GEMM2: eo = w_p * (e1 @ We2[e] + be2)  (plain fp16)
  mgemm_k<0,2,2,64,EXPSZ/128><<<dim3((BATCH/128)*(EXPSZ/128), 1, NEXP), blk, 0, stream>>>(
      e1b, nullptr, We2t0, nullptr, be2, nullptr, eob, nullptr,
      nullptr, pairW, counts, offs, NPAIR, EXPSZ, EXPSZ);
  mixreduce_k<<<dim3(BATCH, 1, 1), blk, 0, stream>>>(eob, rowPos, mix);

  // towers (fp32)
  gemm32_k<true><<<dim3(BATCH/128, 2, 1), blk, 0, stream>>>(
      mix, tW1, tb1, t1, taskPtr, BATCH, 256, EXPSZ);
  gemm32_k<true><<<dim3(BATCH/128, 1, 1), blk, 0, stream>>>(
      t1, tW2, tb2, t2v, taskPtr, BATCH, 128, 256);
  tower3_k<<<dim3(BATCH/4, 1, 1), blk, 0, stream>>>(t2v, tW3, tb3, taskPtr, out);
}